// Round 2
// baseline (382.887 us; speedup 1.0000x reference)
//
#include <hip/hip_runtime.h>
#include <cstdint>

constexpr int B = 32, C = 256, H = 56, W = 56;
constexpr int HW = H * W;          // 3136
constexpr int WORDS = C / 32;      // 8 u32 words per pixel
constexpr int TAPS = 9;
constexpr int WPC = TAPS * WORDS;  // 72 words of weights per output channel
constexpr int PH = H + 2, PW = W + 2, PHW = PH * PW;  // padded 58x58 = 3364

// ---------------------------------------------------------------------------
// Pack x signs into zero-padded buffer:
//   px[b][ph][pw][wd], ph/pw in [0,58), pad ring = 0 words.
// Thread map: idx = (b, wd, pp) with pp fastest -> reads of channel plane are
// contiguous across the wave (256B/instr). Pad threads write 0 (ws is poisoned
// to 0xAA so this is mandatory).
// ---------------------------------------------------------------------------
__global__ __launch_bounds__(256) void pack_x_kernel(const float* __restrict__ x,
                                                     uint32_t* __restrict__ px) {
    int idx = blockIdx.x * 256 + threadIdx.x;   // B*WORDS*PHW = 861184 exact
    int pp = idx % PHW;
    int r = idx / PHW;
    int wd = r % WORDS;
    int b = r / WORDS;
    int ph = pp / PW, pwp = pp - ph * PW;
    uint32_t bits = 0;
    if (ph >= 1 && ph <= H && pwp >= 1 && pwp <= W) {
        const float* xp = x + ((size_t)b * C + wd * 32) * HW + (size_t)(ph - 1) * W + (pwp - 1);
        #pragma unroll
        for (int i = 0; i < 32; ++i)
            bits |= (xp[(size_t)i * HW] < 0.0f ? (1u << i) : 0u);
    }
    px[((size_t)(b * PH + ph) * PW + pwp) * WORDS + wd] = bits;
}

// ---------------------------------------------------------------------------
// Pack w signs: pw[co][tap][wd]. Also writes basep[co] = 2304 + bias[co]
// (the all-taps-valid additive base, pre-folded for the hot epilogue).
// ---------------------------------------------------------------------------
__global__ __launch_bounds__(256) void pack_w_kernel(const float* __restrict__ wt,
                                                     const float* __restrict__ bias,
                                                     uint32_t* __restrict__ pw,
                                                     float* __restrict__ basep) {
    int idx = blockIdx.x * 256 + threadIdx.x;
    if (idx < C) basep[idx] = 2304.0f + bias[idx];
    if (idx >= C * WPC) return;
    int co = idx / WPC;
    int r = idx - co * WPC;
    int tap = r / WORDS;
    int wd = r - tap * WORDS;
    const float* wp = wt + ((size_t)co * C + wd * 32) * TAPS + tap;
    uint32_t bits = 0;
    #pragma unroll
    for (int i = 0; i < 32; ++i)
        bits |= (wp[(size_t)i * TAPS] < 0.0f ? (1u << i) : 0u);
    pw[(size_t)co * WPC + (size_t)tap * WORDS + wd] = bits;
}

// ---------------------------------------------------------------------------
// Main conv, interior formula only (borders fixed up afterwards).
// Block = 256 threads = 4 waves; each wave owns a 64-co chunk
// (readfirstlane keeps weight/base addresses scalar -> SMEM pipe).
// Wave lane = one of 64 consecutive hw. Inner loop per co:
// 72 xor + 72 accumulating popc + 3 add + cvt + fma + store.
// ---------------------------------------------------------------------------
__global__ __launch_bounds__(256) void bconv_kernel(const uint32_t* __restrict__ px,
                                                    const uint32_t* __restrict__ pw,
                                                    const float* __restrict__ basep,
                                                    float* __restrict__ out) {
    const int lane = threadIdx.x & 63;
    const int wid = __builtin_amdgcn_readfirstlane(threadIdx.x >> 6);
    const int hw = blockIdx.x * 64 + lane;      // 3136 = 49*64 exact
    const int b = blockIdx.y;
    const int h = hw / W;
    const int w = hw - h * W;

    uint32_t pxr[TAPS][WORDS];
    #pragma unroll
    for (int dh = -1; dh <= 1; ++dh) {
        #pragma unroll
        for (int dw = -1; dw <= 1; ++dw) {
            const int t = (dh + 1) * 3 + (dw + 1);
            const uint4* p = reinterpret_cast<const uint4*>(
                px + ((size_t)(b * PH + (h + 1 + dh)) * PW + (w + 1 + dw)) * WORDS);
            uint4 a = p[0], q = p[1];
            pxr[t][0] = a.x; pxr[t][1] = a.y; pxr[t][2] = a.z; pxr[t][3] = a.w;
            pxr[t][4] = q.x; pxr[t][5] = q.y; pxr[t][6] = q.z; pxr[t][7] = q.w;
        }
    }

    const int cobase = wid * 64;
    const uint32_t* wbase = pw + (size_t)cobase * WPC;       // scalar
    const float* bbase = basep + cobase;                     // scalar
    float* op = out + ((size_t)b * C + cobase) * HW + hw;

    #pragma unroll 1
    for (int j = 0; j < 64; ++j) {
        const uint32_t* wr = wbase + (size_t)j * WPC;        // wave-uniform
        uint32_t acc[4] = {0u, 0u, 0u, 0u};
        #pragma unroll
        for (int t = 0; t < TAPS; ++t) {
            #pragma unroll
            for (int k = 0; k < WORDS; ++k)
                acc[(t * WORDS + k) & 3] += __popc(pxr[t][k] ^ wr[t * WORDS + k]);
        }
        uint32_t total = (acc[0] + acc[1]) + (acc[2] + acc[3]);
        float res = fmaf(-2.0f, (float)(int)total, bbase[j]);
        op[(size_t)j * HW] = res;
    }
}

// ---------------------------------------------------------------------------
// Border fixup: recompute the 220 border pixels per image exactly
// (256*nvalid - 2*sum_valid popc + bias) and overwrite. Runs after bconv
// on the same stream -> ordering guaranteed.
// ---------------------------------------------------------------------------
__global__ __launch_bounds__(256) void border_kernel(const uint32_t* __restrict__ px,
                                                     const uint32_t* __restrict__ pw,
                                                     const float* __restrict__ bias,
                                                     float* __restrict__ out) {
    int idx = blockIdx.x * 256 + threadIdx.x;   // 32*256*220 = 1802240 exact
    int e = idx % 220;
    int r = idx / 220;
    int co = r & 255;
    int b = r >> 8;
    int h, w;
    if (e < 56)       { h = 0;            w = e; }
    else if (e < 112) { h = 55;           w = e - 56; }
    else if (e < 166) { h = 1 + (e - 112); w = 0; }
    else              { h = 1 + (e - 166); w = 55; }

    const uint32_t* wr = pw + (size_t)co * WPC;
    uint32_t total = 0;
    int nvalid = 0;
    #pragma unroll
    for (int dh = -1; dh <= 1; ++dh) {
        #pragma unroll
        for (int dw = -1; dw <= 1; ++dw) {
            const int t = (dh + 1) * 3 + (dw + 1);
            const int hh = h + dh, ww = w + dw;
            const bool v = (hh >= 0) & (hh < H) & (ww >= 0) & (ww < W);
            const uint32_t* p = px + ((size_t)(b * PH + (hh + 1)) * PW + (ww + 1)) * WORDS;
            uint32_t pt = 0;
            #pragma unroll
            for (int k = 0; k < WORDS; ++k)
                pt += __popc(p[k] ^ wr[t * WORDS + k]);
            total += v ? pt : 0u;
            nvalid += v ? 1 : 0;
        }
    }
    float res = (float)(256 * nvalid) - 2.0f * (float)(int)total + bias[co];
    out[((size_t)b * C + co) * HW + (size_t)h * W + w] = res;
}

extern "C" void kernel_launch(void* const* d_in, const int* in_sizes, int n_in,
                              void* d_out, int out_size, void* d_ws, size_t ws_size,
                              hipStream_t stream) {
    const float* x = (const float*)d_in[0];
    const float* wt = (const float*)d_in[1];
    const float* bias = (const float*)d_in[2];
    float* out = (float*)d_out;

    uint32_t* px = (uint32_t*)d_ws;                       // 32*58*58*8*4 = 3,444,736 B
    uint32_t* pw = px + (size_t)B * PHW * WORDS;          // + 73,728 B
    float* basep = (float*)(pw + (size_t)C * WPC);        // + 1,024 B

    pack_x_kernel<<<(B * WORDS * PHW) / 256, 256, 0, stream>>>(x, px);
    pack_w_kernel<<<(C * WPC + 255) / 256, 256, 0, stream>>>(wt, bias, pw, basep);

    dim3 grid(HW / 64, B);
    bconv_kernel<<<grid, 256, 0, stream>>>(px, pw, basep, out);

    border_kernel<<<(B * C * 220) / 256, 256, 0, stream>>>(px, pw, bias, out);
}